// Round 23
// baseline (121.713 us; speedup 1.0000x reference)
//
#include <hip/hip_runtime.h>
#include <hip/hip_bf16.h>

#define B_ 16
#define C_ 512
#define N_ 1024
#define KL 256
#define HEADS_ 8
#define DH_ 64

typedef __attribute__((ext_vector_type(8))) short bf16x8;
typedef __attribute__((ext_vector_type(4))) float f32x4;
typedef __attribute__((ext_vector_type(16))) float f32x16;

__device__ inline short f2bf(float f) {
  __hip_bfloat16 h = __float2bfloat16(f);
  return *reinterpret_cast<short*>(&h);
}

__device__ inline float bf2f(short s) {
  union { unsigned int u; float f; } c;
  c.u = ((unsigned int)(unsigned short)s) << 16;
  return c.f;
}

__device__ inline void gload16(const void* g, void* l) {
  __builtin_amdgcn_global_load_lds(
      (const __attribute__((address_space(1))) void*)g,
      (__attribute__((address_space(3))) void*)l, 16, 0, 0);
}

// ---------------- merged: GN stats pass1 (blocks 0..1023) + weight prep (1024..1289)
__global__ __launch_bounds__(256) void stats_prep(
    const float* __restrict__ x, float2* __restrict__ part,
    const float* __restrict__ w_qkv, const float* __restrict__ w_proj,
    const float* __restrict__ w_o, const float* __restrict__ E,
    const float* __restrict__ F, const float* __restrict__ b_o,
    const float* __restrict__ b_proj,
    short* __restrict__ wqkv_b, short* __restrict__ wproj_b,
    short* __restrict__ woT_b, short* __restrict__ Et, short* __restrict__ Ft,
    float* __restrict__ esum, float* __restrict__ fsum, float* __restrict__ b2) {
  __shared__ float tl[64 * 65];
  __shared__ float red[8];
  __shared__ float cs[4][64];
  int bid = blockIdx.x;
  const int tid = threadIdx.x;

  if (bid < 1024) {  // GN stats slice
    const int lane = tid & 63, wid = tid >> 6;
    const float4* b4 = (const float4*)(x + (long long)bid * 8192);
    float s = 0.f, sq = 0.f;
#pragma unroll
    for (int j = 0; j < 8; ++j) {
      float4 v = b4[tid + j * 256];
      s += v.x + v.y + v.z + v.w;
      sq += v.x * v.x + v.y * v.y + v.z * v.z + v.w * v.w;
    }
#pragma unroll
    for (int m = 1; m < 64; m <<= 1) {
      s += __shfl_xor(s, m);
      sq += __shfl_xor(sq, m);
    }
    if (lane == 0) { red[wid] = s; red[4 + wid] = sq; }
    __syncthreads();
    if (tid == 0)
      part[bid] = make_float2(red[0] + red[1] + red[2] + red[3],
                              red[4] + red[5] + red[6] + red[7]);
    return;
  }
  bid -= 1024;

  if (bid < 64) {  // dtype converts
    const float4* src;
    short4* dst;
    if (bid < 48) { src = (const float4*)w_qkv + bid * 4096; dst = (short4*)wqkv_b + bid * 4096; }
    else          { src = (const float4*)w_proj + (bid - 48) * 4096; dst = (short4*)wproj_b + (bid - 48) * 4096; }
#pragma unroll
    for (int i = 0; i < 16; ++i) {
      float4 v = src[tid + i * 256];
      short4 p; p.x = f2bf(v.x); p.y = f2bf(v.y); p.z = f2bf(v.z); p.w = f2bf(v.w);
      dst[tid + i * 256] = p;
    }
    return;
  }
  bid -= 64;
  if (bid < 192) {  // transposes: w_o (64), E (64), F (64)
    const float* src; short* dst; int sN, tr, tc;
    if (bid < 64) { src = w_o; dst = woT_b; sN = 512; tr = bid >> 3; tc = bid & 7; }
    else if (bid < 128) { src = E; dst = Et; sN = 256; tr = (bid - 64) & 15; tc = (bid - 64) >> 4; }
    else { src = F; dst = Ft; sN = 256; tr = (bid - 128) & 15; tc = (bid - 128) >> 4; }
    const int R = (sN == 512) ? 512 : 1024;
#pragma unroll 4
    for (int i = 0; i < 16; ++i) {
      const int idx = tid + i * 256;
      const int rl = idx >> 6, cl = idx & 63;
      tl[rl * 65 + cl] = src[(tr * 64 + rl) * sN + tc * 64 + cl];
    }
    __syncthreads();
#pragma unroll 4
    for (int i = 0; i < 16; ++i) {
      const int idx = tid + i * 256;
      const int cl = idx >> 6, rl = idx & 63;
      dst[(tc * 64 + cl) * R + tr * 64 + rl] = f2bf(tl[rl * 65 + cl]);
    }
    return;
  }
  bid -= 192;
  if (bid < 8) {  // colsum
    const float* src = (bid < 4) ? E : F;
    float* dst = (bid < 4) ? esum : fsum;
    const int cb = (bid & 3) * 64;
    const int col = cb + (tid & 63), seg = tid >> 6;
    float s = 0.f;
    for (int n = seg * 256; n < seg * 256 + 256; ++n) s += src[n * 256 + col];
    cs[seg][tid & 63] = s;
    __syncthreads();
    if (tid < 64) dst[cb + tid] = cs[0][tid] + cs[1][tid] + cs[2][tid] + cs[3][tid];
    return;
  }
  bid -= 8;
  {  // b2[o] = b_proj[o] + w_proj[o,:]·b_o  (float4-vectorized row read)
    const int o = bid * 256 + tid;
    const float4* wr = (const float4*)(w_proj + o * 512);
    float s = b_proj[o];
#pragma unroll 4
    for (int m = 0; m < 128; ++m) {
      float4 wv = wr[m];
      s += wv.x * b_o[4 * m] + wv.y * b_o[4 * m + 1] +
           wv.z * b_o[4 * m + 2] + wv.w * b_o[4 * m + 3];
    }
    b2[o] = s;
  }
}

// ---------------- GroupNorm apply (stats finalize inlined per block)
__global__ __launch_bounds__(256) void gn_apply(
    const float* __restrict__ x, const float* __restrict__ gamma,
    const float* __restrict__ beta, const float2* __restrict__ part,
    short* __restrict__ xnc, short* __restrict__ xnT) {
  const int t = blockIdx.x, g = blockIdx.y, b = blockIdx.z;
  float s = 0.f, sq = 0.f;
#pragma unroll
  for (int j = 0; j < 8; ++j) {
    float2 p = part[(b * 8 + g) * 8 + j];
    s += p.x; sq += p.y;
  }
  const float mu = s * (1.f / 65536.f);
  const float var = sq * (1.f / 65536.f) - mu * mu;
  const float rs = rsqrtf(var + 1e-5f);

  __shared__ short tile[64 * 65];
#pragma unroll
  for (int i = 0; i < 4; ++i) {
    const int idx = threadIdx.x + i * 256;
    const int cl = idx >> 4;
    const int nl0 = (idx & 15) * 4;
    const int ch = g * 64 + cl;
    const long long gi = ((long long)(b * C_ + ch)) * N_ + t * 64 + nl0;
    const float4 v = *(const float4*)(x + gi);
    const float gm = gamma[ch], bt = beta[ch];
    short s0 = f2bf((v.x - mu) * rs * gm + bt);
    short s1 = f2bf((v.y - mu) * rs * gm + bt);
    short s2 = f2bf((v.z - mu) * rs * gm + bt);
    short s3 = f2bf((v.w - mu) * rs * gm + bt);
    short4 pk; pk.x = s0; pk.y = s1; pk.z = s2; pk.w = s3;
    *(short4*)(xnc + gi) = pk;
    tile[cl * 65 + nl0] = s0;
    tile[cl * 65 + nl0 + 1] = s1;
    tile[cl * 65 + nl0 + 2] = s2;
    tile[cl * 65 + nl0 + 3] = s3;
  }
  __syncthreads();

#pragma unroll
  for (int i = 0; i < 4; ++i) {
    const int idx = threadIdx.x + i * 256;
    const int cl0 = (idx & 15) * 4;
    const int nl = idx >> 4;
    short4 pk;
    pk.x = tile[(cl0 + 0) * 65 + nl];
    pk.y = tile[(cl0 + 1) * 65 + nl];
    pk.z = tile[(cl0 + 2) * 65 + nl];
    pk.w = tile[(cl0 + 3) * 65 + nl];
    *(short4*)(xnT + ((long long)b * N_ + t * 64 + nl) * C_ + g * 64 + cl0) = pk;
  }
}

// ---------------- single-job GEMM (S5): C[M][Nn] = A * Bt^T, BM template.
template <int BM, int BIAS_MODE, bool OUT_BF16, bool RESID>
__global__ __launch_bounds__(256) void gemm_bt(
    const short* __restrict__ A, const short* __restrict__ Bt,
    void* __restrict__ Cout, const float* __restrict__ bias,
    const float* __restrict__ bias2, const short* __restrict__ resid,
    int M, int Nn, int Kd, long long sA, long long sB, long long sC) {
  constexpr int AR = BM / 32;
  constexpr int WR = BM / 2;
  const int gx = gridDim.x, gy = gridDim.y;
  const int nwg = gx * gy * gridDim.z;
  const int bid = blockIdx.x + gx * (blockIdx.y + gy * blockIdx.z);
  const int cpx = nwg >> 3;
  int w = (bid & 7) * cpx + (bid >> 3);
  const int mx = w % gx; w /= gx;
  const int ny = w % gy;
  const int bz = w / gy;

  const int m0 = mx * BM;
  const int n0 = ny * 64;
  const short* Ab = A + bz * sA;
  const short* Bb = Bt + bz * sB;
  const int tid = threadIdx.x;
  const int lane = tid & 63;
  const int wid = tid >> 6;
  const int wm = wid >> 1, wn = wid & 1;

  __shared__ __align__(16) short As[BM * 64];
  __shared__ __align__(16) short Bs[64 * 64];

  f32x4 acc[AR][2] = {};

  for (int kt = 0; kt < Kd; kt += 64) {
#pragma unroll
    for (int r = 0; r < AR; ++r) {
      const int dbase = r * 4096 + wid * 1024;
      const int dbyte = dbase + (lane << 4);
      const int row = dbyte >> 7;
      const int chunk = ((dbyte >> 4) & 7) ^ (row & 7);
      gload16(Ab + (long long)(m0 + row) * Kd + kt + chunk * 8, (char*)As + dbase);
    }
#pragma unroll
    for (int r = 0; r < 2; ++r) {
      const int dbase = r * 4096 + wid * 1024;
      const int dbyte = dbase + (lane << 4);
      const int row = dbyte >> 7;
      const int chunk = ((dbyte >> 4) & 7) ^ (row & 7);
      gload16(Bb + (long long)(n0 + row) * Kd + kt + chunk * 8, (char*)Bs + dbase);
    }
    __syncthreads();
#pragma unroll
    for (int kk = 0; kk < 2; ++kk) {
      bf16x8 af[AR], bfr[2];
#pragma unroll
      for (int mi = 0; mi < AR; ++mi) {
        int row = wm * WR + mi * 16 + (lane & 15);
        int chunk = (kk * 4 + (lane >> 4)) ^ (row & 7);
        af[mi] = *(const bf16x8*)(As + row * 64 + chunk * 8);
      }
#pragma unroll
      for (int ni = 0; ni < 2; ++ni) {
        int row = wn * 32 + ni * 16 + (lane & 15);
        int chunk = (kk * 4 + (lane >> 4)) ^ (row & 7);
        bfr[ni] = *(const bf16x8*)(Bs + row * 64 + chunk * 8);
      }
#pragma unroll
      for (int mi = 0; mi < AR; ++mi)
#pragma unroll
        for (int ni = 0; ni < 2; ++ni)
          acc[mi][ni] = __builtin_amdgcn_mfma_f32_16x16x32_bf16(af[mi], bfr[ni], acc[mi][ni], 0, 0, 0);
    }
    __syncthreads();
  }

#pragma unroll
  for (int mi = 0; mi < AR; ++mi) {
#pragma unroll
    for (int ni = 0; ni < 2; ++ni) {
      const int row = m0 + wm * WR + mi * 16 + ((lane >> 4) << 2);
      const int col = n0 + wn * 32 + ni * 16 + (lane & 15);
      f32x4 v = acc[mi][ni];
#pragma unroll
      for (int j = 0; j < 4; ++j) {
        float val = v[j];
        if (BIAS_MODE == 1) val += bias[row + j];
        if (BIAS_MODE == 2) val += bias[col];
        if (BIAS_MODE == 3) val += bias[row + j] * bias2[col];
        const long long ci = (long long)bz * sC + (long long)(row + j) * Nn + col;
        if (RESID) val += bf2f(resid[ci]);
        if (OUT_BF16) ((short*)Cout)[ci] = f2bf(val);
        else ((float*)Cout)[ci] = val;
      }
    }
  }
}

// ---------------- twin-job GEMM (kp, vp): BM-templated (128 — inside the
// merge, combined residency is batch-supplied, so tile density wins).
template <int BM, int BIAS_MODE, bool OUT_BF16>
__global__ __launch_bounds__(256) void gemm_bt2(
    const short* A0, const short* Bt0, void* C0,
    const float* bias0, const float* bias20,
    int Nn0, int Kd0, long long sA0, long long sB0, long long sC0,
    int gx0, int gy0, int nblk0,
    const short* A1, const short* Bt1, void* C1,
    const float* bias1, const float* bias21,
    int Nn1, int Kd1, long long sA1, long long sB1, long long sC1,
    int gx1, int gy1, int nblk1) {
  constexpr int AR = BM / 32;
  constexpr int WR = BM / 2;
  int bid = blockIdx.x;
  const bool j1 = bid >= nblk0;
  if (j1) bid -= nblk0;
  const short* A     = j1 ? A1 : A0;
  const short* Bt    = j1 ? Bt1 : Bt0;
  void* Cout         = j1 ? C1 : C0;
  const float* bias  = j1 ? bias1 : bias0;
  const float* bias2 = j1 ? bias21 : bias20;
  const int Nn       = j1 ? Nn1 : Nn0;
  const int Kd       = j1 ? Kd1 : Kd0;
  const long long sA = j1 ? sA1 : sA0;
  const long long sB = j1 ? sB1 : sB0;
  const long long sC = j1 ? sC1 : sC0;
  const int gx       = j1 ? gx1 : gx0;
  const int gy       = j1 ? gy1 : gy0;
  const int nblk     = j1 ? nblk1 : nblk0;

  const int cpx = nblk >> 3;
  int w = (bid & 7) * cpx + (bid >> 3);
  const int mx = w % gx; w /= gx;
  const int ny = w % gy;
  const int bz = w / gy;

  const int m0 = mx * BM;
  const int n0 = ny * 64;
  const short* Ab = A + bz * sA;
  const short* Bb = Bt + bz * sB;
  const int tid = threadIdx.x;
  const int lane = tid & 63;
  const int wid = tid >> 6;
  const int wm = wid >> 1, wn = wid & 1;

  __shared__ __align__(16) short As[BM * 64];
  __shared__ __align__(16) short Bs[64 * 64];

  f32x4 acc[AR][2] = {};

  for (int kt = 0; kt < Kd; kt += 64) {
#pragma unroll
    for (int r = 0; r < AR; ++r) {
      const int dbase = r * 4096 + wid * 1024;
      const int dbyte = dbase + (lane << 4);
      const int row = dbyte >> 7;
      const int chunk = ((dbyte >> 4) & 7) ^ (row & 7);
      gload16(Ab + (long long)(m0 + row) * Kd + kt + chunk * 8, (char*)As + dbase);
    }
#pragma unroll
    for (int r = 0; r < 2; ++r) {
      const int dbase = r * 4096 + wid * 1024;
      const int dbyte = dbase + (lane << 4);
      const int row = dbyte >> 7;
      const int chunk = ((dbyte >> 4) & 7) ^ (row & 7);
      gload16(Bb + (long long)(n0 + row) * Kd + kt + chunk * 8, (char*)Bs + dbase);
    }
    __syncthreads();
#pragma unroll
    for (int kk = 0; kk < 2; ++kk) {
      bf16x8 af[AR], bfr[2];
#pragma unroll
      for (int mi = 0; mi < AR; ++mi) {
        int row = wm * WR + mi * 16 + (lane & 15);
        int chunk = (kk * 4 + (lane >> 4)) ^ (row & 7);
        af[mi] = *(const bf16x8*)(As + row * 64 + chunk * 8);
      }
#pragma unroll
      for (int ni = 0; ni < 2; ++ni) {
        int row = wn * 32 + ni * 16 + (lane & 15);
        int chunk = (kk * 4 + (lane >> 4)) ^ (row & 7);
        bfr[ni] = *(const bf16x8*)(Bs + row * 64 + chunk * 8);
      }
#pragma unroll
      for (int mi = 0; mi < AR; ++mi)
#pragma unroll
        for (int ni = 0; ni < 2; ++ni)
          acc[mi][ni] = __builtin_amdgcn_mfma_f32_16x16x32_bf16(af[mi], bfr[ni], acc[mi][ni], 0, 0, 0);
    }
    __syncthreads();
  }

#pragma unroll
  for (int mi = 0; mi < AR; ++mi) {
#pragma unroll
    for (int ni = 0; ni < 2; ++ni) {
      const int row = m0 + wm * WR + mi * 16 + ((lane >> 4) << 2);
      const int col = n0 + wn * 32 + ni * 16 + (lane & 15);
      f32x4 v = acc[mi][ni];
#pragma unroll
      for (int j = 0; j < 4; ++j) {
        float val = v[j];
        if (BIAS_MODE == 1) val += bias[row + j];
        if (BIAS_MODE == 2) val += bias[col];
        if (BIAS_MODE == 3) val += bias[row + j] * bias2[col];
        const long long ci = (long long)bz * sC + (long long)(row + j) * Nn + col;
        if (OUT_BF16) ((short*)Cout)[ci] = f2bf(val);
        else ((float*)Cout)[ci] = val;
      }
    }
  }
}

// ---------------- triple-job GEMM (q, xEF, wcomb): BM-templated (128),
// runtime bias_mode (0 or 2, epilogue-only), bf16 out. 3-way uniform ternary
// selection (s_cselect chains, SGPR-resident — rule #20 safe).
template <int BM>
__global__ __launch_bounds__(256) void gemm_bt3(
    const short* A0, const short* Bt0, void* C0, const float* bias0,
    int Nn0, int Kd0, long long sA0, long long sB0, long long sC0,
    int gx0, int gy0, int nblk0, int bm0,
    const short* A1, const short* Bt1, void* C1, const float* bias1,
    int Nn1, int Kd1, long long sA1, long long sB1, long long sC1,
    int gx1, int gy1, int nblk1, int bm1,
    const short* A2, const short* Bt2, void* C2, const float* bias2,
    int Nn2, int Kd2, long long sA2, long long sB2, long long sC2,
    int gx2, int gy2, int nblk2, int bm2) {
  constexpr int AR = BM / 32;
  constexpr int WR = BM / 2;
  int bid = blockIdx.x;
  int sel = 0;
  if (bid >= nblk0) {
    bid -= nblk0; sel = 1;
    if (bid >= nblk1) { bid -= nblk1; sel = 2; }
  }
#define P3(f) (sel == 0 ? f##0 : (sel == 1 ? f##1 : f##2))
  const short* A    = P3(A);
  const short* Bt   = P3(Bt);
  void* Cout        = P3(C);
  const float* bias = P3(bias);
  const int Nn      = P3(Nn);
  const int Kd      = P3(Kd);
  const long long sA = P3(sA);
  const long long sB = P3(sB);
  const long long sC = P3(sC);
  const int gx      = P3(gx);
  const int gy      = P3(gy);
  const int nblk    = P3(nblk);
  const int bmode   = P3(bm);
#undef P3

  const int cpx = nblk >> 3;
  int w = (bid & 7) * cpx + (bid >> 3);
  const int mx = w % gx; w /= gx;
  const int ny = w % gy;
  const int bz = w / gy;

  const int m0 = mx * BM;
  const int n0 = ny * 64;
  const short* Ab = A + bz * sA;
  const short* Bb = Bt + bz * sB;
  const int tid = threadIdx.x;
  const int lane = tid & 63;
  const int wid = tid >> 6;
  const int wm = wid >> 1, wn = wid & 1;

  __shared__ __align__(16) short As[BM * 64];
  __shared__ __align__(16) short Bs[64 * 64];

  f32x4 acc[AR][2] = {};

  for (int kt = 0; kt < Kd; kt += 64) {
#pragma unroll
    for (int r = 0; r < AR; ++r) {
      const int dbase = r * 4096 + wid * 1024;
      const int dbyte = dbase + (lane << 4);
      const int row = dbyte >> 7;
      const int chunk = ((dbyte >> 4) & 7) ^ (row & 7);
      gload16(Ab + (long long)(m0 + row) * Kd + kt + chunk * 8, (char*)As + dbase);
    }
#pragma unroll
    for (int r = 0; r < 2; ++r) {
      const int dbase = r * 4096 + wid * 1024;
      const int dbyte = dbase + (lane << 4);
      const int row = dbyte >> 7;
      const int chunk = ((dbyte >> 4) & 7) ^ (row & 7);
      gload16(Bb + (long long)(n0 + row) * Kd + kt + chunk * 8, (char*)Bs + dbase);
    }
    __syncthreads();
#pragma unroll
    for (int kk = 0; kk < 2; ++kk) {
      bf16x8 af[AR], bfr[2];
#pragma unroll
      for (int mi = 0; mi < AR; ++mi) {
        int row = wm * WR + mi * 16 + (lane & 15);
        int chunk = (kk * 4 + (lane >> 4)) ^ (row & 7);
        af[mi] = *(const bf16x8*)(As + row * 64 + chunk * 8);
      }
#pragma unroll
      for (int ni = 0; ni < 2; ++ni) {
        int row = wn * 32 + ni * 16 + (lane & 15);
        int chunk = (kk * 4 + (lane >> 4)) ^ (row & 7);
        bfr[ni] = *(const bf16x8*)(Bs + row * 64 + chunk * 8);
      }
#pragma unroll
      for (int mi = 0; mi < AR; ++mi)
#pragma unroll
        for (int ni = 0; ni < 2; ++ni)
          acc[mi][ni] = __builtin_amdgcn_mfma_f32_16x16x32_bf16(af[mi], bfr[ni], acc[mi][ni], 0, 0, 0);
    }
    __syncthreads();
  }

#pragma unroll
  for (int mi = 0; mi < AR; ++mi) {
#pragma unroll
    for (int ni = 0; ni < 2; ++ni) {
      const int row = m0 + wm * WR + mi * 16 + ((lane >> 4) << 2);
      const int col = n0 + wn * 32 + ni * 16 + (lane & 15);
      f32x4 v = acc[mi][ni];
#pragma unroll
      for (int j = 0; j < 4; ++j) {
        float val = v[j];
        if (bmode == 2) val += bias[col];
        const long long ci = (long long)bz * sC + (long long)(row + j) * Nn + col;
        ((short*)Cout)[ci] = f2bf(val);
      }
    }
  }
}

// ---------------- fused Linformer attention, 32x32 swapped-QK, in-register softmax
// T5: s_setprio(1) around MFMA clusters — waves drift barrier-free here (the
// m191-positive regime: role diversity across waves on a CU).
__global__ __launch_bounds__(512, 4) void attn_fused32(
    const short* __restrict__ q, const short* __restrict__ kp,
    const short* __restrict__ vp, short* __restrict__ o) {
  const int qt = blockIdx.x;
  const int h = blockIdx.y;
  const int b = blockIdx.z;
  const int tid = threadIdx.x;
  const int lane = tid & 63;
  const int wid = tid >> 6;
  const int nlo = lane & 31;
  const int hi = lane >> 5;

  __shared__ __align__(16) short kbuf[256 * 64];
  __shared__ __align__(16) short vbuf[64 * 256];

  {
    const short* base = kp + (long long)b * (KL * C_) + h * DH_;
#pragma unroll
    for (int i = 0; i < 4; ++i) {
      const int dbyte = (i * 512 + tid) * 16;
      const int row = dbyte >> 7;
      const int chunk = ((dbyte >> 4) & 7) ^ (row & 7);
      gload16(base + row * C_ + chunk * 8, (char*)kbuf + dbyte);
    }
  }
  {
    const short* base = vp + ((long long)b * C_ + h * DH_) * KL;
#pragma unroll
    for (int i = 0; i < 4; ++i) {
      const int dbyte = (i * 512 + tid) * 16;
      const int row = dbyte >> 9;
      const int chunk = ((dbyte >> 4) & 31) ^ (row & 7);
      gload16(base + row * KL + chunk * 8, (char*)vbuf + dbyte);
    }
  }

  const int n0 = qt * 256 + wid * 32;
  bf16x8 bq[4];
  {
    const short* qb = q + ((long long)b * N_ + n0 + nlo) * C_ + h * DH_ + hi * 8;
#pragma unroll
    for (int dk = 0; dk < 4; ++dk) bq[dk] = *(const bf16x8*)(qb + dk * 16);
  }
  __syncthreads();

  f32x16 oa0, oa1;
#pragma unroll
  for (int r = 0; r < 16; ++r) { oa0[r] = 0.f; oa1[r] = 0.f; }
  float mrun = -1e30f, lrun = 0.f;

#pragma unroll
  for (int kb = 0; kb < 8; ++kb) {
    f32x16 s;
#pragma unroll
    for (int r = 0; r < 16; ++r) s[r] = 0.f;
    __builtin_amdgcn_s_setprio(1);
#pragma unroll
    for (int dk = 0; dk < 4; ++dk) {
      const int row = kb * 32 + nlo;
      bf16x8 ak = *(const bf16x8*)(kbuf + row * 64 + (((dk * 2 + hi) ^ (nlo & 7)) * 8));
      s = __builtin_amdgcn_mfma_f32_32x32x16_bf16(ak, bq[dk], s, 0, 0, 0);
    }
    __builtin_amdgcn_s_setprio(0);
    float lm = -1e30f;
#pragma unroll
    for (int r = 0; r < 16; ++r) { s[r] *= 0.125f; lm = fmaxf(lm, s[r]); }
    lm = fmaxf(lm, __shfl_xor(lm, 32));
    const float mnew = fmaxf(mrun, lm);
    const float sc_old = __expf(mrun - mnew);
    float ls = 0.f;
#pragma unroll
    for (int r = 0; r < 16; ++r) {
      float p = __expf(s[r] - mnew);
      s[r] = p;
      ls += p;
    }
    ls += __shfl_xor(ls, 32);
    lrun = lrun * sc_old + ls;
    mrun = mnew;
#pragma unroll
    for (int r = 0; r < 16; ++r) { oa0[r] *= sc_old; oa1[r] *= sc_old; }

    unsigned int w[8];
#pragma unroll
    for (int i = 0; i < 8; ++i) {
      float plo = s[2 * i], phi = s[2 * i + 1];
      unsigned int pk;
      asm("v_cvt_pk_bf16_f32 %0, %1, %2" : "=v"(pk) : "v"(plo), "v"(phi));
      w[i] = pk;
    }
    __builtin_amdgcn_s_setprio(1);
#pragma unroll
    for (int m = 0; m < 2; ++m) {
      unsigned int u0 = w[4 * m + 0], u1 = w[4 * m + 1];
      unsigned int u2 = w[4 * m + 2], u3 = w[4 * m + 3];
      asm volatile("v_permlane32_swap_b32 %0, %1" : "+v"(u0), "+v"(u2));
      asm volatile("v_permlane32_swap_b32 %0, %1" : "+v"(u1), "+v"(u3));
      union { unsigned int u[4]; bf16x8 v; } bp;
      bp.u[0] = u0; bp.u[1] = u1; bp.u[2] = u2; bp.u[3] = u3;
      const int ck = ((kb * 4 + m * 2 + hi) ^ (nlo & 7)) * 8;
      bf16x8 av0 = *(const bf16x8*)(vbuf + (nlo) * 256 + ck);
      bf16x8 av1 = *(const bf16x8*)(vbuf + (32 + nlo) * 256 + ck);
      oa0 = __builtin_amdgcn_mfma_f32_32x32x16_bf16(av0, bp.v, oa0, 0, 0, 0);
      oa1 = __builtin_amdgcn_mfma_f32_32x32x16_bf16(av1, bp.v, oa1, 0, 0, 0);
    }
    __builtin_amdgcn_s_setprio(0);
  }

  const float rinv = 1.f / lrun;
  short* ob = o + ((long long)b * N_ + n0 + nlo) * C_ + h * DH_;
#pragma unroll
  for (int a = 0; a < 4; ++a) {
    short4 p0, p1;
    p0.x = f2bf(oa0[4 * a + 0] * rinv); p0.y = f2bf(oa0[4 * a + 1] * rinv);
    p0.z = f2bf(oa0[4 * a + 2] * rinv); p0.w = f2bf(oa0[4 * a + 3] * rinv);
    p1.x = f2bf(oa1[4 * a + 0] * rinv); p1.y = f2bf(oa1[4 * a + 1] * rinv);
    p1.z = f2bf(oa1[4 * a + 2] * rinv); p1.w = f2bf(oa1[4 * a + 3] * rinv);
    *(short4*)(ob + a * 8 + hi * 4) = p0;
    *(short4*)(ob + 32 + a * 8 + hi * 4) = p1;
  }
}

extern "C" void kernel_launch(void* const* d_in, const int* in_sizes, int n_in,
                              void* d_out, int out_size, void* d_ws, size_t ws_size,
                              hipStream_t stream) {
  (void)in_sizes; (void)n_in; (void)out_size; (void)ws_size;
  const float* x      = (const float*)d_in[0];
  const float* gamma  = (const float*)d_in[1];
  const float* beta   = (const float*)d_in[2];
  const float* w_qkv  = (const float*)d_in[3];
  const float* b_qkv  = (const float*)d_in[4];
  const float* E      = (const float*)d_in[5];
  const float* F      = (const float*)d_in[6];
  const float* w_o    = (const float*)d_in[7];
  const float* b_o    = (const float*)d_in[8];
  const float* w_proj = (const float*)d_in[9];
  const float* b_proj = (const float*)d_in[10];
  float* out = (float*)d_out;

  char* ws = (char*)d_ws;
  short* xnc    = (short*)ws;  ws += 16777216LL;   // [16][512][1024] bf16
  short* xnT    = (short*)ws;  ws += 16777216LL;   // [16][1024][512] bf16 (later: attno)
  short* qbuf   = (short*)ws;  ws += 16777216LL;   // [16][1024][512] bf16
  short* xEF    = (short*)ws;  ws += 8388608LL;    // [16][512][512] bf16 (xE 0-255, xF 256-511)
  short* kpb    = (short*)ws;  ws += 4194304LL;    // [16][256][512] bf16
  short* vpb    = (short*)ws;  ws += 4194304LL;    // [16][512][256] bf16
  short* wqkv_b = (short*)ws;  ws += 1572864LL;    // [1536][512] bf16
  short* wproj_b= (short*)ws;  ws += 524288LL;     // [512][512] bf16
  short* woT_b  = (short*)ws;  ws += 524288LL;     // [512][512] bf16 (w_o^T)
  short* wcomb_b= (short*)ws;  ws += 524288LL;     // [512][512] bf16 (w_proj*w_o)
  short* etft   = (short*)ws;  ws += 1048576LL;    // [512][1024] bf16 (Et; Ft at +256 rows)
  float2* part  = (float2*)ws; ws += 8192LL;       // [1024]
  float* esum   = (float*)ws;  ws += 1024LL;       // [256]
  float* fsum   = (float*)ws;  ws += 1024LL;       // [256]
  float* b2     = (float*)ws;  ws += 2048LL;       // [512]
  short* attno  = xnT;                             // alias
  short* Et     = etft;
  short* Ft     = etft + 262144;

  // 1: GN stats + ALL weight prep
  stats_prep<<<dim3(1290), dim3(256), 0, stream>>>(
      x, part, w_qkv, w_proj, w_o, E, F, b_o, b_proj,
      wqkv_b, wproj_b, woT_b, Et, Ft, esum, fsum, b2);

  // 2: GN apply
  gn_apply<<<dim3(16, 8, 16), dim3(256), 0, stream>>>(x, gamma, beta, part, xnc, xnT);

  // 3: triple {q (1024 blk), xEF (512 blk), wcomb (32 blk)} @ BM=128 — 1568 blocks
  gemm_bt3<128><<<dim3(1568), dim3(256), 0, stream>>>(
      xnT, wqkv_b, qbuf, b_qkv,
      512, 512, 524288LL, 0LL, 524288LL, 8, 8, 1024, 2,
      etft, xnc, xEF, nullptr,
      512, 1024, 0LL, 524288LL, 262144LL, 4, 8, 512, 0,
      wproj_b, woT_b, wcomb_b, nullptr,
      512, 512, 0LL, 0LL, 0LL, 4, 8, 32, 0);

  // 4: twin {kp (256 blk), vp (256 blk)} @ BM=128 — 512 blocks
  gemm_bt2<128, 3, true><<<dim3(512), dim3(256), 0, stream>>>(
      xEF, wqkv_b + 262144, kpb, esum, b_qkv + 512,
      512, 512, 262144LL, 0LL, 131072LL, 2, 8, 256,
      wqkv_b + 524288, xEF + 131072, vpb, b_qkv + 1024, fsum,
      256, 512, 0LL, 262144LL, 131072LL, 4, 4, 256);

  // 5: attention (+T5 setprio)
  attn_fused32<<<dim3(4, 8, 16), dim3(512), 0, stream>>>(qbuf, kpb, vpb, attno);

  // 6: S5: out[b][o][n] = wcomb * attno[b]^T + b2[row] + xnc   (128x64: 1024 blocks)
  gemm_bt<128, 1, false, true><<<dim3(4, 16, 16), dim3(256), 0, stream>>>(
      wcomb_b, attno, out, b2, nullptr, xnc,
      512, 1024, 512, 0LL, 524288LL, 524288LL);
}

// Round 24
// 116.411 us; speedup vs baseline: 1.0455x; 1.0455x over previous
//
#include <hip/hip_runtime.h>
#include <hip/hip_bf16.h>

#define B_ 16
#define C_ 512
#define N_ 1024
#define KL 256
#define HEADS_ 8
#define DH_ 64

typedef __attribute__((ext_vector_type(8))) short bf16x8;
typedef __attribute__((ext_vector_type(4))) float f32x4;
typedef __attribute__((ext_vector_type(16))) float f32x16;

__device__ inline short f2bf(float f) {
  __hip_bfloat16 h = __float2bfloat16(f);
  return *reinterpret_cast<short*>(&h);
}

__device__ inline float bf2f(short s) {
  union { unsigned int u; float f; } c;
  c.u = ((unsigned int)(unsigned short)s) << 16;
  return c.f;
}

__device__ inline void gload16(const void* g, void* l) {
  __builtin_amdgcn_global_load_lds(
      (const __attribute__((address_space(1))) void*)g,
      (__attribute__((address_space(3))) void*)l, 16, 0, 0);
}

// ---------------- merged: GN stats pass1 (blocks 0..1023) + weight prep (1024..1289)
__global__ __launch_bounds__(256) void stats_prep(
    const float* __restrict__ x, float2* __restrict__ part,
    const float* __restrict__ w_qkv, const float* __restrict__ w_proj,
    const float* __restrict__ w_o, const float* __restrict__ E,
    const float* __restrict__ F, const float* __restrict__ b_o,
    const float* __restrict__ b_proj,
    short* __restrict__ wqkv_b, short* __restrict__ wproj_b,
    short* __restrict__ woT_b, short* __restrict__ Et, short* __restrict__ Ft,
    float* __restrict__ esum, float* __restrict__ fsum, float* __restrict__ b2) {
  __shared__ float tl[64 * 65];
  __shared__ float red[8];
  __shared__ float cs[4][64];
  int bid = blockIdx.x;
  const int tid = threadIdx.x;

  if (bid < 1024) {  // GN stats slice
    const int lane = tid & 63, wid = tid >> 6;
    const float4* b4 = (const float4*)(x + (long long)bid * 8192);
    float s = 0.f, sq = 0.f;
#pragma unroll
    for (int j = 0; j < 8; ++j) {
      float4 v = b4[tid + j * 256];
      s += v.x + v.y + v.z + v.w;
      sq += v.x * v.x + v.y * v.y + v.z * v.z + v.w * v.w;
    }
#pragma unroll
    for (int m = 1; m < 64; m <<= 1) {
      s += __shfl_xor(s, m);
      sq += __shfl_xor(sq, m);
    }
    if (lane == 0) { red[wid] = s; red[4 + wid] = sq; }
    __syncthreads();
    if (tid == 0)
      part[bid] = make_float2(red[0] + red[1] + red[2] + red[3],
                              red[4] + red[5] + red[6] + red[7]);
    return;
  }
  bid -= 1024;

  if (bid < 64) {  // dtype converts
    const float4* src;
    short4* dst;
    if (bid < 48) { src = (const float4*)w_qkv + bid * 4096; dst = (short4*)wqkv_b + bid * 4096; }
    else          { src = (const float4*)w_proj + (bid - 48) * 4096; dst = (short4*)wproj_b + (bid - 48) * 4096; }
#pragma unroll
    for (int i = 0; i < 16; ++i) {
      float4 v = src[tid + i * 256];
      short4 p; p.x = f2bf(v.x); p.y = f2bf(v.y); p.z = f2bf(v.z); p.w = f2bf(v.w);
      dst[tid + i * 256] = p;
    }
    return;
  }
  bid -= 64;
  if (bid < 192) {  // transposes: w_o (64), E (64), F (64)
    const float* src; short* dst; int sN, tr, tc;
    if (bid < 64) { src = w_o; dst = woT_b; sN = 512; tr = bid >> 3; tc = bid & 7; }
    else if (bid < 128) { src = E; dst = Et; sN = 256; tr = (bid - 64) & 15; tc = (bid - 64) >> 4; }
    else { src = F; dst = Ft; sN = 256; tr = (bid - 128) & 15; tc = (bid - 128) >> 4; }
    const int R = (sN == 512) ? 512 : 1024;
#pragma unroll 4
    for (int i = 0; i < 16; ++i) {
      const int idx = tid + i * 256;
      const int rl = idx >> 6, cl = idx & 63;
      tl[rl * 65 + cl] = src[(tr * 64 + rl) * sN + tc * 64 + cl];
    }
    __syncthreads();
#pragma unroll 4
    for (int i = 0; i < 16; ++i) {
      const int idx = tid + i * 256;
      const int cl = idx >> 6, rl = idx & 63;
      dst[(tc * 64 + cl) * R + tr * 64 + rl] = f2bf(tl[rl * 65 + cl]);
    }
    return;
  }
  bid -= 192;
  if (bid < 8) {  // colsum
    const float* src = (bid < 4) ? E : F;
    float* dst = (bid < 4) ? esum : fsum;
    const int cb = (bid & 3) * 64;
    const int col = cb + (tid & 63), seg = tid >> 6;
    float s = 0.f;
    for (int n = seg * 256; n < seg * 256 + 256; ++n) s += src[n * 256 + col];
    cs[seg][tid & 63] = s;
    __syncthreads();
    if (tid < 64) dst[cb + tid] = cs[0][tid] + cs[1][tid] + cs[2][tid] + cs[3][tid];
    return;
  }
  bid -= 8;
  {  // b2[o] = b_proj[o] + w_proj[o,:]·b_o  (float4-vectorized row read)
    const int o = bid * 256 + tid;
    const float4* wr = (const float4*)(w_proj + o * 512);
    float s = b_proj[o];
#pragma unroll 4
    for (int m = 0; m < 128; ++m) {
      float4 wv = wr[m];
      s += wv.x * b_o[4 * m] + wv.y * b_o[4 * m + 1] +
           wv.z * b_o[4 * m + 2] + wv.w * b_o[4 * m + 3];
    }
    b2[o] = s;
  }
}

// ---------------- GroupNorm apply (stats finalize inlined per block)
__global__ __launch_bounds__(256) void gn_apply(
    const float* __restrict__ x, const float* __restrict__ gamma,
    const float* __restrict__ beta, const float2* __restrict__ part,
    short* __restrict__ xnc, short* __restrict__ xnT) {
  const int t = blockIdx.x, g = blockIdx.y, b = blockIdx.z;
  float s = 0.f, sq = 0.f;
#pragma unroll
  for (int j = 0; j < 8; ++j) {
    float2 p = part[(b * 8 + g) * 8 + j];
    s += p.x; sq += p.y;
  }
  const float mu = s * (1.f / 65536.f);
  const float var = sq * (1.f / 65536.f) - mu * mu;
  const float rs = rsqrtf(var + 1e-5f);

  __shared__ short tile[64 * 65];
#pragma unroll
  for (int i = 0; i < 4; ++i) {
    const int idx = threadIdx.x + i * 256;
    const int cl = idx >> 4;
    const int nl0 = (idx & 15) * 4;
    const int ch = g * 64 + cl;
    const long long gi = ((long long)(b * C_ + ch)) * N_ + t * 64 + nl0;
    const float4 v = *(const float4*)(x + gi);
    const float gm = gamma[ch], bt = beta[ch];
    short s0 = f2bf((v.x - mu) * rs * gm + bt);
    short s1 = f2bf((v.y - mu) * rs * gm + bt);
    short s2 = f2bf((v.z - mu) * rs * gm + bt);
    short s3 = f2bf((v.w - mu) * rs * gm + bt);
    short4 pk; pk.x = s0; pk.y = s1; pk.z = s2; pk.w = s3;
    *(short4*)(xnc + gi) = pk;
    tile[cl * 65 + nl0] = s0;
    tile[cl * 65 + nl0 + 1] = s1;
    tile[cl * 65 + nl0 + 2] = s2;
    tile[cl * 65 + nl0 + 3] = s3;
  }
  __syncthreads();

#pragma unroll
  for (int i = 0; i < 4; ++i) {
    const int idx = threadIdx.x + i * 256;
    const int cl0 = (idx & 15) * 4;
    const int nl = idx >> 4;
    short4 pk;
    pk.x = tile[(cl0 + 0) * 65 + nl];
    pk.y = tile[(cl0 + 1) * 65 + nl];
    pk.z = tile[(cl0 + 2) * 65 + nl];
    pk.w = tile[(cl0 + 3) * 65 + nl];
    *(short4*)(xnT + ((long long)b * N_ + t * 64 + nl) * C_ + g * 64 + cl0) = pk;
  }
}

// ---------------- single-job GEMM (S5): C[M][Nn] = A * Bt^T, BM template.
template <int BM, int BIAS_MODE, bool OUT_BF16, bool RESID>
__global__ __launch_bounds__(256) void gemm_bt(
    const short* __restrict__ A, const short* __restrict__ Bt,
    void* __restrict__ Cout, const float* __restrict__ bias,
    const float* __restrict__ bias2, const short* __restrict__ resid,
    int M, int Nn, int Kd, long long sA, long long sB, long long sC) {
  constexpr int AR = BM / 32;
  constexpr int WR = BM / 2;
  const int gx = gridDim.x, gy = gridDim.y;
  const int nwg = gx * gy * gridDim.z;
  const int bid = blockIdx.x + gx * (blockIdx.y + gy * blockIdx.z);
  const int cpx = nwg >> 3;
  int w = (bid & 7) * cpx + (bid >> 3);
  const int mx = w % gx; w /= gx;
  const int ny = w % gy;
  const int bz = w / gy;

  const int m0 = mx * BM;
  const int n0 = ny * 64;
  const short* Ab = A + bz * sA;
  const short* Bb = Bt + bz * sB;
  const int tid = threadIdx.x;
  const int lane = tid & 63;
  const int wid = tid >> 6;
  const int wm = wid >> 1, wn = wid & 1;

  __shared__ __align__(16) short As[BM * 64];
  __shared__ __align__(16) short Bs[64 * 64];

  f32x4 acc[AR][2] = {};

  for (int kt = 0; kt < Kd; kt += 64) {
#pragma unroll
    for (int r = 0; r < AR; ++r) {
      const int dbase = r * 4096 + wid * 1024;
      const int dbyte = dbase + (lane << 4);
      const int row = dbyte >> 7;
      const int chunk = ((dbyte >> 4) & 7) ^ (row & 7);
      gload16(Ab + (long long)(m0 + row) * Kd + kt + chunk * 8, (char*)As + dbase);
    }
#pragma unroll
    for (int r = 0; r < 2; ++r) {
      const int dbase = r * 4096 + wid * 1024;
      const int dbyte = dbase + (lane << 4);
      const int row = dbyte >> 7;
      const int chunk = ((dbyte >> 4) & 7) ^ (row & 7);
      gload16(Bb + (long long)(n0 + row) * Kd + kt + chunk * 8, (char*)Bs + dbase);
    }
    __syncthreads();
#pragma unroll
    for (int kk = 0; kk < 2; ++kk) {
      bf16x8 af[AR], bfr[2];
#pragma unroll
      for (int mi = 0; mi < AR; ++mi) {
        int row = wm * WR + mi * 16 + (lane & 15);
        int chunk = (kk * 4 + (lane >> 4)) ^ (row & 7);
        af[mi] = *(const bf16x8*)(As + row * 64 + chunk * 8);
      }
#pragma unroll
      for (int ni = 0; ni < 2; ++ni) {
        int row = wn * 32 + ni * 16 + (lane & 15);
        int chunk = (kk * 4 + (lane >> 4)) ^ (row & 7);
        bfr[ni] = *(const bf16x8*)(Bs + row * 64 + chunk * 8);
      }
#pragma unroll
      for (int mi = 0; mi < AR; ++mi)
#pragma unroll
        for (int ni = 0; ni < 2; ++ni)
          acc[mi][ni] = __builtin_amdgcn_mfma_f32_16x16x32_bf16(af[mi], bfr[ni], acc[mi][ni], 0, 0, 0);
    }
    __syncthreads();
  }

#pragma unroll
  for (int mi = 0; mi < AR; ++mi) {
#pragma unroll
    for (int ni = 0; ni < 2; ++ni) {
      const int row = m0 + wm * WR + mi * 16 + ((lane >> 4) << 2);
      const int col = n0 + wn * 32 + ni * 16 + (lane & 15);
      f32x4 v = acc[mi][ni];
#pragma unroll
      for (int j = 0; j < 4; ++j) {
        float val = v[j];
        if (BIAS_MODE == 1) val += bias[row + j];
        if (BIAS_MODE == 2) val += bias[col];
        if (BIAS_MODE == 3) val += bias[row + j] * bias2[col];
        const long long ci = (long long)bz * sC + (long long)(row + j) * Nn + col;
        if (RESID) val += bf2f(resid[ci]);
        if (OUT_BF16) ((short*)Cout)[ci] = f2bf(val);
        else ((float*)Cout)[ci] = val;
      }
    }
  }
}

// ---------------- twin-job GEMM (kp, vp): 64x64 tiles (r20-proven optimum —
// many small blocks beat dense blocks in this latency-bound regime; r23
// falsified BM=128-in-merge at 42us vs 26us).
template <int BIAS_MODE, bool OUT_BF16>
__global__ __launch_bounds__(256) void gemm_bt2(
    const short* A0, const short* Bt0, void* C0,
    const float* bias0, const float* bias20,
    int Nn0, int Kd0, long long sA0, long long sB0, long long sC0,
    int gx0, int gy0, int nblk0,
    const short* A1, const short* Bt1, void* C1,
    const float* bias1, const float* bias21,
    int Nn1, int Kd1, long long sA1, long long sB1, long long sC1,
    int gx1, int gy1, int nblk1) {
  int bid = blockIdx.x;
  const bool j1 = bid >= nblk0;
  if (j1) bid -= nblk0;
  const short* A     = j1 ? A1 : A0;
  const short* Bt    = j1 ? Bt1 : Bt0;
  void* Cout         = j1 ? C1 : C0;
  const float* bias  = j1 ? bias1 : bias0;
  const float* bias2 = j1 ? bias21 : bias20;
  const int Nn       = j1 ? Nn1 : Nn0;
  const int Kd       = j1 ? Kd1 : Kd0;
  const long long sA = j1 ? sA1 : sA0;
  const long long sB = j1 ? sB1 : sB0;
  const long long sC = j1 ? sC1 : sC0;
  const int gx       = j1 ? gx1 : gx0;
  const int gy       = j1 ? gy1 : gy0;
  const int nblk     = j1 ? nblk1 : nblk0;

  const int cpx = nblk >> 3;
  int w = (bid & 7) * cpx + (bid >> 3);
  const int mx = w % gx; w /= gx;
  const int ny = w % gy;
  const int bz = w / gy;

  const int m0 = mx * 64;
  const int n0 = ny * 64;
  const short* Ab = A + bz * sA;
  const short* Bb = Bt + bz * sB;
  const int tid = threadIdx.x;
  const int lane = tid & 63;
  const int wid = tid >> 6;
  const int wm = wid >> 1, wn = wid & 1;

  __shared__ __align__(16) short As[64 * 64];
  __shared__ __align__(16) short Bs[64 * 64];

  f32x4 acc[2][2] = {};

  for (int kt = 0; kt < Kd; kt += 64) {
#pragma unroll
    for (int r = 0; r < 2; ++r) {
      const int dbase = r * 4096 + wid * 1024;
      const int dbyte = dbase + (lane << 4);
      const int row = dbyte >> 7;
      const int chunk = ((dbyte >> 4) & 7) ^ (row & 7);
      gload16(Ab + (long long)(m0 + row) * Kd + kt + chunk * 8, (char*)As + dbase);
      gload16(Bb + (long long)(n0 + row) * Kd + kt + chunk * 8, (char*)Bs + dbase);
    }
    __syncthreads();
#pragma unroll
    for (int kk = 0; kk < 2; ++kk) {
      bf16x8 af[2], bfr[2];
#pragma unroll
      for (int mi = 0; mi < 2; ++mi) {
        int row = wm * 32 + mi * 16 + (lane & 15);
        int chunk = (kk * 4 + (lane >> 4)) ^ (row & 7);
        af[mi] = *(const bf16x8*)(As + row * 64 + chunk * 8);
      }
#pragma unroll
      for (int ni = 0; ni < 2; ++ni) {
        int row = wn * 32 + ni * 16 + (lane & 15);
        int chunk = (kk * 4 + (lane >> 4)) ^ (row & 7);
        bfr[ni] = *(const bf16x8*)(Bs + row * 64 + chunk * 8);
      }
#pragma unroll
      for (int mi = 0; mi < 2; ++mi)
#pragma unroll
        for (int ni = 0; ni < 2; ++ni)
          acc[mi][ni] = __builtin_amdgcn_mfma_f32_16x16x32_bf16(af[mi], bfr[ni], acc[mi][ni], 0, 0, 0);
    }
    __syncthreads();
  }

#pragma unroll
  for (int mi = 0; mi < 2; ++mi) {
#pragma unroll
    for (int ni = 0; ni < 2; ++ni) {
      const int row = m0 + wm * 32 + mi * 16 + ((lane >> 4) << 2);
      const int col = n0 + wn * 32 + ni * 16 + (lane & 15);
      f32x4 v = acc[mi][ni];
#pragma unroll
      for (int j = 0; j < 4; ++j) {
        float val = v[j];
        if (BIAS_MODE == 1) val += bias[row + j];
        if (BIAS_MODE == 2) val += bias[col];
        if (BIAS_MODE == 3) val += bias[row + j] * bias2[col];
        const long long ci = (long long)bz * sC + (long long)(row + j) * Nn + col;
        if (OUT_BF16) ((short*)Cout)[ci] = f2bf(val);
        else ((float*)Cout)[ci] = val;
      }
    }
  }
}

// ---------------- triple-job GEMM (q, xEF, wcomb): 64x64 tiles, runtime
// bias_mode (0 or 2, epilogue-only), bf16 out. 3-way uniform ternary selection
// (s_cselect chains, SGPR-resident — rule #20 safe; r18/r20-validated).
__global__ __launch_bounds__(256) void gemm_bt3(
    const short* A0, const short* Bt0, void* C0, const float* bias0,
    int Nn0, int Kd0, long long sA0, long long sB0, long long sC0,
    int gx0, int gy0, int nblk0, int bm0,
    const short* A1, const short* Bt1, void* C1, const float* bias1,
    int Nn1, int Kd1, long long sA1, long long sB1, long long sC1,
    int gx1, int gy1, int nblk1, int bm1,
    const short* A2, const short* Bt2, void* C2, const float* bias2,
    int Nn2, int Kd2, long long sA2, long long sB2, long long sC2,
    int gx2, int gy2, int nblk2, int bm2) {
  int bid = blockIdx.x;
  int sel = 0;
  if (bid >= nblk0) {
    bid -= nblk0; sel = 1;
    if (bid >= nblk1) { bid -= nblk1; sel = 2; }
  }
#define P3(f) (sel == 0 ? f##0 : (sel == 1 ? f##1 : f##2))
  const short* A    = P3(A);
  const short* Bt   = P3(Bt);
  void* Cout        = P3(C);
  const float* bias = P3(bias);
  const int Nn      = P3(Nn);
  const int Kd      = P3(Kd);
  const long long sA = P3(sA);
  const long long sB = P3(sB);
  const long long sC = P3(sC);
  const int gx      = P3(gx);
  const int gy      = P3(gy);
  const int nblk    = P3(nblk);
  const int bmode   = P3(bm);
#undef P3

  const int cpx = nblk >> 3;
  int w = (bid & 7) * cpx + (bid >> 3);
  const int mx = w % gx; w /= gx;
  const int ny = w % gy;
  const int bz = w / gy;

  const int m0 = mx * 64;
  const int n0 = ny * 64;
  const short* Ab = A + bz * sA;
  const short* Bb = Bt + bz * sB;
  const int tid = threadIdx.x;
  const int lane = tid & 63;
  const int wid = tid >> 6;
  const int wm = wid >> 1, wn = wid & 1;

  __shared__ __align__(16) short As[64 * 64];
  __shared__ __align__(16) short Bs[64 * 64];

  f32x4 acc[2][2] = {};

  for (int kt = 0; kt < Kd; kt += 64) {
#pragma unroll
    for (int r = 0; r < 2; ++r) {
      const int dbase = r * 4096 + wid * 1024;
      const int dbyte = dbase + (lane << 4);
      const int row = dbyte >> 7;
      const int chunk = ((dbyte >> 4) & 7) ^ (row & 7);
      gload16(Ab + (long long)(m0 + row) * Kd + kt + chunk * 8, (char*)As + dbase);
      gload16(Bb + (long long)(n0 + row) * Kd + kt + chunk * 8, (char*)Bs + dbase);
    }
    __syncthreads();
#pragma unroll
    for (int kk = 0; kk < 2; ++kk) {
      bf16x8 af[2], bfr[2];
#pragma unroll
      for (int mi = 0; mi < 2; ++mi) {
        int row = wm * 32 + mi * 16 + (lane & 15);
        int chunk = (kk * 4 + (lane >> 4)) ^ (row & 7);
        af[mi] = *(const bf16x8*)(As + row * 64 + chunk * 8);
      }
#pragma unroll
      for (int ni = 0; ni < 2; ++ni) {
        int row = wn * 32 + ni * 16 + (lane & 15);
        int chunk = (kk * 4 + (lane >> 4)) ^ (row & 7);
        bfr[ni] = *(const bf16x8*)(Bs + row * 64 + chunk * 8);
      }
#pragma unroll
      for (int mi = 0; mi < 2; ++mi)
#pragma unroll
        for (int ni = 0; ni < 2; ++ni)
          acc[mi][ni] = __builtin_amdgcn_mfma_f32_16x16x32_bf16(af[mi], bfr[ni], acc[mi][ni], 0, 0, 0);
    }
    __syncthreads();
  }

#pragma unroll
  for (int mi = 0; mi < 2; ++mi) {
#pragma unroll
    for (int ni = 0; ni < 2; ++ni) {
      const int row = m0 + wm * 32 + mi * 16 + ((lane >> 4) << 2);
      const int col = n0 + wn * 32 + ni * 16 + (lane & 15);
      f32x4 v = acc[mi][ni];
#pragma unroll
      for (int j = 0; j < 4; ++j) {
        float val = v[j];
        if (bmode == 2) val += bias[col];
        const long long ci = (long long)bz * sC + (long long)(row + j) * Nn + col;
        ((short*)Cout)[ci] = f2bf(val);
      }
    }
  }
}

// ---------------- fused Linformer attention, 32x32 swapped-QK, in-register softmax
__global__ __launch_bounds__(512, 4) void attn_fused32(
    const short* __restrict__ q, const short* __restrict__ kp,
    const short* __restrict__ vp, short* __restrict__ o) {
  const int qt = blockIdx.x;
  const int h = blockIdx.y;
  const int b = blockIdx.z;
  const int tid = threadIdx.x;
  const int lane = tid & 63;
  const int wid = tid >> 6;
  const int nlo = lane & 31;
  const int hi = lane >> 5;

  __shared__ __align__(16) short kbuf[256 * 64];
  __shared__ __align__(16) short vbuf[64 * 256];

  {
    const short* base = kp + (long long)b * (KL * C_) + h * DH_;
#pragma unroll
    for (int i = 0; i < 4; ++i) {
      const int dbyte = (i * 512 + tid) * 16;
      const int row = dbyte >> 7;
      const int chunk = ((dbyte >> 4) & 7) ^ (row & 7);
      gload16(base + row * C_ + chunk * 8, (char*)kbuf + dbyte);
    }
  }
  {
    const short* base = vp + ((long long)b * C_ + h * DH_) * KL;
#pragma unroll
    for (int i = 0; i < 4; ++i) {
      const int dbyte = (i * 512 + tid) * 16;
      const int row = dbyte >> 9;
      const int chunk = ((dbyte >> 4) & 31) ^ (row & 7);
      gload16(base + row * KL + chunk * 8, (char*)vbuf + dbyte);
    }
  }

  const int n0 = qt * 256 + wid * 32;
  bf16x8 bq[4];
  {
    const short* qb = q + ((long long)b * N_ + n0 + nlo) * C_ + h * DH_ + hi * 8;
#pragma unroll
    for (int dk = 0; dk < 4; ++dk) bq[dk] = *(const bf16x8*)(qb + dk * 16);
  }
  __syncthreads();

  f32x16 oa0, oa1;
#pragma unroll
  for (int r = 0; r < 16; ++r) { oa0[r] = 0.f; oa1[r] = 0.f; }
  float mrun = -1e30f, lrun = 0.f;

#pragma unroll
  for (int kb = 0; kb < 8; ++kb) {
    f32x16 s;
#pragma unroll
    for (int r = 0; r < 16; ++r) s[r] = 0.f;
#pragma unroll
    for (int dk = 0; dk < 4; ++dk) {
      const int row = kb * 32 + nlo;
      bf16x8 ak = *(const bf16x8*)(kbuf + row * 64 + (((dk * 2 + hi) ^ (nlo & 7)) * 8));
      s = __builtin_amdgcn_mfma_f32_32x32x16_bf16(ak, bq[dk], s, 0, 0, 0);
    }
    float lm = -1e30f;
#pragma unroll
    for (int r = 0; r < 16; ++r) { s[r] *= 0.125f; lm = fmaxf(lm, s[r]); }
    lm = fmaxf(lm, __shfl_xor(lm, 32));
    const float mnew = fmaxf(mrun, lm);
    const float sc_old = __expf(mrun - mnew);
    float ls = 0.f;
#pragma unroll
    for (int r = 0; r < 16; ++r) {
      float p = __expf(s[r] - mnew);
      s[r] = p;
      ls += p;
    }
    ls += __shfl_xor(ls, 32);
    lrun = lrun * sc_old + ls;
    mrun = mnew;
#pragma unroll
    for (int r = 0; r < 16; ++r) { oa0[r] *= sc_old; oa1[r] *= sc_old; }

    unsigned int w[8];
#pragma unroll
    for (int i = 0; i < 8; ++i) {
      float plo = s[2 * i], phi = s[2 * i + 1];
      unsigned int pk;
      asm("v_cvt_pk_bf16_f32 %0, %1, %2" : "=v"(pk) : "v"(plo), "v"(phi));
      w[i] = pk;
    }
#pragma unroll
    for (int m = 0; m < 2; ++m) {
      unsigned int u0 = w[4 * m + 0], u1 = w[4 * m + 1];
      unsigned int u2 = w[4 * m + 2], u3 = w[4 * m + 3];
      asm volatile("v_permlane32_swap_b32 %0, %1" : "+v"(u0), "+v"(u2));
      asm volatile("v_permlane32_swap_b32 %0, %1" : "+v"(u1), "+v"(u3));
      union { unsigned int u[4]; bf16x8 v; } bp;
      bp.u[0] = u0; bp.u[1] = u1; bp.u[2] = u2; bp.u[3] = u3;
      const int ck = ((kb * 4 + m * 2 + hi) ^ (nlo & 7)) * 8;
      bf16x8 av0 = *(const bf16x8*)(vbuf + (nlo) * 256 + ck);
      bf16x8 av1 = *(const bf16x8*)(vbuf + (32 + nlo) * 256 + ck);
      oa0 = __builtin_amdgcn_mfma_f32_32x32x16_bf16(av0, bp.v, oa0, 0, 0, 0);
      oa1 = __builtin_amdgcn_mfma_f32_32x32x16_bf16(av1, bp.v, oa1, 0, 0, 0);
    }
  }

  const float rinv = 1.f / lrun;
  short* ob = o + ((long long)b * N_ + n0 + nlo) * C_ + h * DH_;
#pragma unroll
  for (int a = 0; a < 4; ++a) {
    short4 p0, p1;
    p0.x = f2bf(oa0[4 * a + 0] * rinv); p0.y = f2bf(oa0[4 * a + 1] * rinv);
    p0.z = f2bf(oa0[4 * a + 2] * rinv); p0.w = f2bf(oa0[4 * a + 3] * rinv);
    p1.x = f2bf(oa1[4 * a + 0] * rinv); p1.y = f2bf(oa1[4 * a + 1] * rinv);
    p1.z = f2bf(oa1[4 * a + 2] * rinv); p1.w = f2bf(oa1[4 * a + 3] * rinv);
    *(short4*)(ob + a * 8 + hi * 4) = p0;
    *(short4*)(ob + 32 + a * 8 + hi * 4) = p1;
  }
}

extern "C" void kernel_launch(void* const* d_in, const int* in_sizes, int n_in,
                              void* d_out, int out_size, void* d_ws, size_t ws_size,
                              hipStream_t stream) {
  (void)in_sizes; (void)n_in; (void)out_size; (void)ws_size;
  const float* x      = (const float*)d_in[0];
  const float* gamma  = (const float*)d_in[1];
  const float* beta   = (const float*)d_in[2];
  const float* w_qkv  = (const float*)d_in[3];
  const float* b_qkv  = (const float*)d_in[4];
  const float* E      = (const float*)d_in[5];
  const float* F      = (const float*)d_in[6];
  const float* w_o    = (const float*)d_in[7];
  const float* b_o    = (const float*)d_in[8];
  const float* w_proj = (const float*)d_in[9];
  const float* b_proj = (const float*)d_in[10];
  float* out = (float*)d_out;

  char* ws = (char*)d_ws;
  short* xnc    = (short*)ws;  ws += 16777216LL;   // [16][512][1024] bf16
  short* xnT    = (short*)ws;  ws += 16777216LL;   // [16][1024][512] bf16 (later: attno)
  short* qbuf   = (short*)ws;  ws += 16777216LL;   // [16][1024][512] bf16
  short* xEF    = (short*)ws;  ws += 8388608LL;    // [16][512][512] bf16 (xE 0-255, xF 256-511)
  short* kpb    = (short*)ws;  ws += 4194304LL;    // [16][256][512] bf16
  short* vpb    = (short*)ws;  ws += 4194304LL;    // [16][512][256] bf16
  short* wqkv_b = (short*)ws;  ws += 1572864LL;    // [1536][512] bf16
  short* wproj_b= (short*)ws;  ws += 524288LL;     // [512][512] bf16
  short* woT_b  = (short*)ws;  ws += 524288LL;     // [512][512] bf16 (w_o^T)
  short* wcomb_b= (short*)ws;  ws += 524288LL;     // [512][512] bf16 (w_proj*w_o)
  short* etft   = (short*)ws;  ws += 1048576LL;    // [512][1024] bf16 (Et; Ft at +256 rows)
  float2* part  = (float2*)ws; ws += 8192LL;       // [1024]
  float* esum   = (float*)ws;  ws += 1024LL;       // [256]
  float* fsum   = (float*)ws;  ws += 1024LL;       // [256]
  float* b2     = (float*)ws;  ws += 2048LL;       // [512]
  short* attno  = xnT;                             // alias
  short* Et     = etft;
  short* Ft     = etft + 262144;

  // 1: GN stats + ALL weight prep
  stats_prep<<<dim3(1290), dim3(256), 0, stream>>>(
      x, part, w_qkv, w_proj, w_o, E, F, b_o, b_proj,
      wqkv_b, wproj_b, woT_b, Et, Ft, esum, fsum, b2);

  // 2: GN apply
  gn_apply<<<dim3(16, 8, 16), dim3(256), 0, stream>>>(x, gamma, beta, part, xnc, xnT);

  // 3: triple {q (2048 blk), xEF (1024 blk), wcomb (64 blk)} — 3136 blocks (r20 optimum)
  gemm_bt3<<<dim3(3136), dim3(256), 0, stream>>>(
      xnT, wqkv_b, qbuf, b_qkv,
      512, 512, 524288LL, 0LL, 524288LL, 16, 8, 2048, 2,
      etft, xnc, xEF, nullptr,
      512, 1024, 0LL, 524288LL, 262144LL, 8, 8, 1024, 0,
      wproj_b, woT_b, wcomb_b, nullptr,
      512, 512, 0LL, 0LL, 0LL, 8, 8, 64, 0);

  // 4: twin {kp (512 blk), vp (512 blk)} — 1024 blocks (r20 optimum)
  gemm_bt2<3, true><<<dim3(1024), dim3(256), 0, stream>>>(
      xEF, wqkv_b + 262144, kpb, esum, b_qkv + 512,
      512, 512, 262144LL, 0LL, 131072LL, 4, 8, 512,
      wqkv_b + 524288, xEF + 131072, vpb, b_qkv + 1024, fsum,
      256, 512, 0LL, 262144LL, 131072LL, 8, 4, 512);

  // 5: attention
  attn_fused32<<<dim3(4, 8, 16), dim3(512), 0, stream>>>(qbuf, kpb, vpb, attno);

  // 6: S5: out[b][o][n] = wcomb * attno[b]^T + b2[row] + xnc   (128x64: 1024 blocks)
  gemm_bt<128, 1, false, true><<<dim3(4, 16, 16), dim3(256), 0, stream>>>(
      wcomb_b, attno, out, b2, nullptr, xnc,
      512, 1024, 512, 0LL, 524288LL, 524288LL);
}